// Round 10
// baseline (211.163 us; speedup 1.0000x reference)
//
#include <hip/hip_runtime.h>
#include <math.h>

#define BB 8
#define CC 64
#define NN 4096
#define CI 8
#define GAMMA 0.1f
// exp(s/sqrt(8)) = exp2(s * log2(e)/sqrt(8)); folded into k in qkv.
#define SCALE (1.44269504088896f * 0.35355339059327f)
#define NSPLIT 4

typedef float v2f __attribute__((ext_vector_type(2)));
typedef float v4f __attribute__((ext_vector_type(4)));
typedef __bf16 bf16x8 __attribute__((ext_vector_type(8)));

__device__ __forceinline__ float fast_exp2(float x) {
    return __builtin_amdgcn_exp2f(x);
}

// qkv. Grid (NN/32, BB); block 256 = 8 i-groups x 32 n.
// qbh[b][n][8] bf16, kbh[b][m][8] bf16 (k*SCALE), vf[b][n][8] FP32
// (PV is now fp32 VALU in att -> v stays full precision).
// Zeros attab[b][9][N].
__global__ __launch_bounds__(256) void qkv_kernel(
        const float* __restrict__ x,
        const float* __restrict__ Wq, const float* __restrict__ Wk,
        const float* __restrict__ Wv,
        __bf16* __restrict__ qbh, __bf16* __restrict__ kbh,
        float* __restrict__ vf, float* __restrict__ attab) {
    __shared__ float sw[3 * CI * CC];     // 6 KB: Wq | Wk*SCALE | Wv
    __shared__ unsigned short sq[32 * 8]; // bf16 tile [n_local][i]
    __shared__ unsigned short sk[32 * 8];
    __shared__ float sv[32 * 8];          // fp32 tile [n_local][i]
    const int t = threadIdx.x;
    const int i  = t >> 5;
    const int nl = t & 31;
    const int b  = blockIdx.y;
    const int n0 = blockIdx.x * 32;

    for (int idx = t; idx < CI * CC; idx += 256) {
        sw[idx]                = Wq[idx];
        sw[CI * CC + idx]      = Wk[idx] * SCALE;
        sw[2 * CI * CC + idx]  = Wv[idx];
    }
    int lin = (blockIdx.y * (NN / 32) + blockIdx.x) * 256 + t;
    for (int idx = lin; idx < BB * 9 * NN; idx += BB * NN * CI) attab[idx] = 0.f;
    __syncthreads();

    const int n = n0 + nl;
    const float* xp = x + ((size_t)b * CC) * NN + n;
    const v4f* wq4 = (const v4f*)(sw + i * CC);
    const v4f* wk4 = (const v4f*)(sw + CI * CC + i * CC);
    const v4f* wv4 = (const v4f*)(sw + 2 * CI * CC + i * CC);
    float qa = 0.f, ka = 0.f, va = 0.f;
#pragma unroll 4
    for (int c4 = 0; c4 < CC / 4; ++c4) {
        v4f wq = wq4[c4], wk = wk4[c4], wv = wv4[c4];   // LDS broadcast b128
        float x0 = xp[(size_t)(c4 * 4 + 0) * NN];
        float x1 = xp[(size_t)(c4 * 4 + 1) * NN];
        float x2 = xp[(size_t)(c4 * 4 + 2) * NN];
        float x3 = xp[(size_t)(c4 * 4 + 3) * NN];
        qa = fmaf(wq.x, x0, qa); ka = fmaf(wk.x, x0, ka); va = fmaf(wv.x, x0, va);
        qa = fmaf(wq.y, x1, qa); ka = fmaf(wk.y, x1, ka); va = fmaf(wv.y, x1, va);
        qa = fmaf(wq.z, x2, qa); ka = fmaf(wk.z, x2, ka); va = fmaf(wv.z, x2, va);
        qa = fmaf(wq.w, x3, qa); ka = fmaf(wk.w, x3, ka); va = fmaf(wv.w, x3, va);
    }
    __bf16 qb = (__bf16)qa, kb2 = (__bf16)ka;
    sq[nl * 8 + i] = *(unsigned short*)&qb;
    sk[nl * 8 + i] = *(unsigned short*)&kb2;
    sv[nl * 8 + i] = va;
    __syncthreads();
    if (t < 32) {
        *(uint4*)(qbh + ((size_t)b * NN + n0 + t) * 8) = *(const uint4*)(sq + t * 8);
        *(uint4*)(kbh + ((size_t)b * NN + n0 + t) * 8) = *(const uint4*)(sk + t * 8);
    }
    if (t < 64) {   // vf: 32 n x 32B, fully coalesced 1KB store
        int n2 = t >> 1, h = t & 1;
        *(v4f*)(vf + ((size_t)b * NN + n0 + n2) * 8 + h * 4) =
            *(const v4f*)(sv + n2 * 8 + h * 4);
    }
}

// MFMA-S + register-PV attention. NO LDS AT ALL.
// Key fact: after S = Q^T K (mfma_16x16x32, C-layout col=lane&15, row=quad*4+r),
// each lane's 4 scores share the same column m=lm, rows = n. So PV needs no
// transpose: acc[i][m=lm] += e * v[i][n] accumulates in registers (fp32
// pk_fma; v fp32 quad-broadcast loads). This deletes R7-R9's serial
// MFMA->exp->cvt->ds_write->lgkm->ds_read->MFMA chain (the measured latency
// bound: MfmaUtil 11%, VALUBusy 41%) and the bf16-E rounding.
// Epilogue: shfl_xor(16,32) quad-reduction, quad-0 lanes do the 9 atomics.
// |scores| < ~2 -> exp without max-subtraction is safe (shift-invariant).
// Grid (64 m-blocks, NSPLIT, BB) = 2048 blocks x 4 waves.
__global__ __launch_bounds__(256) void att_kernel(
        const __bf16* __restrict__ qbh, const __bf16* __restrict__ kbh,
        const float* __restrict__ vf, float* __restrict__ attab) {
    const int t = threadIdx.x;
    const int w    = t >> 6;
    const int l    = t & 63;
    const int quad = l >> 4;
    const int lm   = l & 15;
    const int b  = blockIdx.z;
    const int m0 = blockIdx.x * 64 + w * 16;
    const int nbase = blockIdx.y * (NN / NSPLIT);

    bf16x8 zero8;
#pragma unroll
    for (int z = 0; z < 8; ++z) zero8[z] = (__bf16)0.0f;

    bf16x8 kfrag = zero8;                 // B[k=quad*8+j][col=lm], k<8 live
    if (quad == 0)
        kfrag = *(const bf16x8*)(kbh + ((size_t)b * NN + m0 + lm) * 8);

    const __bf16* qrow = qbh + (size_t)b * NN * 8;
    const float*  vrow = vf  + (size_t)b * NN * 8;

    v2f acc[4] = {(v2f){0.f,0.f}, (v2f){0.f,0.f}, (v2f){0.f,0.f}, (v2f){0.f,0.f}};
    float es = 0.f;

#pragma unroll 2
    for (int ch = 0; ch < (NN / NSPLIT) / 32; ++ch) {
        const int nc = nbase + ch * 32;
        bf16x8 q0 = zero8, q1 = zero8;    // A[row=lm][k=quad*8+j], k<8 live
        if (quad == 0) {
            q0 = *(const bf16x8*)(qrow + (size_t)(nc + lm) * 8);
            q1 = *(const bf16x8*)(qrow + (size_t)(nc + 16 + lm) * 8);
        }
        v4f s0 = __builtin_amdgcn_mfma_f32_16x16x32_bf16(q0, kfrag, (v4f){0.f,0.f,0.f,0.f}, 0, 0, 0);
        v4f s1 = __builtin_amdgcn_mfma_f32_16x16x32_bf16(q1, kfrag, (v4f){0.f,0.f,0.f,0.f}, 0, 0, 0);

        // lane's scores: rows n = nc + (h?16:0) + quad*4 + r, col m = lm
        const float* vp0 = vrow + (size_t)(nc + quad * 4) * 8;
        const float* vp1 = vrow + (size_t)(nc + 16 + quad * 4) * 8;
        float sv0[4] = {s0.x, s0.y, s0.z, s0.w};
        float sv1[4] = {s1.x, s1.y, s1.z, s1.w};
#pragma unroll
        for (int r = 0; r < 4; ++r) {
            float e = fast_exp2(sv0[r]);
            es += e;
            v4f vlo = *(const v4f*)(vp0 + r * 8);       // quad-broadcast L1/L2
            v4f vhi = *(const v4f*)(vp0 + r * 8 + 4);
            v2f e2 = {e, e};
            acc[0] = __builtin_elementwise_fma(e2, (v2f){vlo.x, vlo.y}, acc[0]);
            acc[1] = __builtin_elementwise_fma(e2, (v2f){vlo.z, vlo.w}, acc[1]);
            acc[2] = __builtin_elementwise_fma(e2, (v2f){vhi.x, vhi.y}, acc[2]);
            acc[3] = __builtin_elementwise_fma(e2, (v2f){vhi.z, vhi.w}, acc[3]);
        }
#pragma unroll
        for (int r = 0; r < 4; ++r) {
            float e = fast_exp2(sv1[r]);
            es += e;
            v4f vlo = *(const v4f*)(vp1 + r * 8);
            v4f vhi = *(const v4f*)(vp1 + r * 8 + 4);
            v2f e2 = {e, e};
            acc[0] = __builtin_elementwise_fma(e2, (v2f){vlo.x, vlo.y}, acc[0]);
            acc[1] = __builtin_elementwise_fma(e2, (v2f){vlo.z, vlo.w}, acc[1]);
            acc[2] = __builtin_elementwise_fma(e2, (v2f){vhi.x, vhi.y}, acc[2]);
            acc[3] = __builtin_elementwise_fma(e2, (v2f){vhi.z, vhi.w}, acc[3]);
        }
    }

    // quad-partials -> full sums (lanes quad^1 at xor16, quad^2 at xor32)
    float vals[9] = {acc[0].x, acc[0].y, acc[1].x, acc[1].y,
                     acc[2].x, acc[2].y, acc[3].x, acc[3].y, es};
#pragma unroll
    for (int i = 0; i < 9; ++i) {
        vals[i] += __shfl_xor(vals[i], 16);
        vals[i] += __shfl_xor(vals[i], 32);
    }
    if (quad == 0) {
        float* ap = attab + (size_t)b * 9 * NN + m0 + lm;
#pragma unroll
        for (int i = 0; i < 9; ++i) atomicAdd(ap + (size_t)i * NN, vals[i]);
    }
}

// out. Grid (NN/1024, CC, BB); block 256; float4 per thread.
__global__ __launch_bounds__(256) void out_kernel(
        const float* __restrict__ x, const float* __restrict__ Wout,
        const float* __restrict__ attab, float* __restrict__ out) {
    const int t = threadIdx.x;
    const int c = blockIdx.y;
    const int b = blockIdx.z;
    const int m = (blockIdx.x * 256 + t) * 4;
    const float* ap = attab + (size_t)b * 9 * NN + m;
    v4f sum = *(const v4f*)(ap + (size_t)8 * NN);
    v4f s = {0.f, 0.f, 0.f, 0.f};
#pragma unroll
    for (int i = 0; i < CI; ++i) {
        float wgt = Wout[c * CI + i];               // uniform -> s_load
        v4f a = *(const v4f*)(ap + (size_t)i * NN);
        s.x = fmaf(wgt, a.x, s.x);
        s.y = fmaf(wgt, a.y, s.y);
        s.z = fmaf(wgt, a.z, s.z);
        s.w = fmaf(wgt, a.w, s.w);
    }
    size_t o = ((size_t)b * CC + c) * NN + m;
    v4f xv = *(const v4f*)(x + o);
    v4f r;
    r.x = xv.x + GAMMA * (s.x / sum.x);
    r.y = xv.y + GAMMA * (s.y / sum.y);
    r.z = xv.z + GAMMA * (s.z / sum.z);
    r.w = xv.w + GAMMA * (s.w / sum.w);
    *(v4f*)(out + o) = r;
}

extern "C" void kernel_launch(void* const* d_in, const int* in_sizes, int n_in,
                              void* d_out, int out_size, void* d_ws, size_t ws_size,
                              hipStream_t stream) {
    const float* x    = (const float*)d_in[0];
    const float* Wq   = (const float*)d_in[1];
    const float* Wk   = (const float*)d_in[2];
    const float* Wv   = (const float*)d_in[3];
    const float* Wout = (const float*)d_in[4];
    float* out = (float*)d_out;

    // ws: qbh [B][N][8] bf16 | kbh [B][N][8] bf16 | vf [B][N][8] fp32 |
    //     attab [B][9][N] fp32
    __bf16* qbh = (__bf16*)d_ws;
    __bf16* kbh = qbh + (size_t)BB * NN * 8;
    float*  vf  = (float*)(kbh + (size_t)BB * NN * 8);
    float* attab = vf + (size_t)BB * NN * 8;

    qkv_kernel<<<dim3(NN / 32, BB), 256, 0, stream>>>(x, Wq, Wk, Wv, qbh, kbh, vf, attab);
    att_kernel<<<dim3(NN / 64, NSPLIT, BB), 256, 0, stream>>>(qbh, kbh, vf, attab);
    out_kernel<<<dim3(NN / 1024, CC, BB), 256, 0, stream>>>(x, Wout, attab, out);
}

// Round 11
// 138.172 us; speedup vs baseline: 1.5283x; 1.5283x over previous
//
#include <hip/hip_runtime.h>
#include <math.h>

#define BB 8
#define CC 64
#define NN 4096
#define CI 8
#define GAMMA 0.1f
// exp(s/sqrt(8)) = exp2(s * log2(e)/sqrt(8)); folded into k in qkv.
#define SCALE (1.44269504088896f * 0.35355339059327f)
#define NSPLIT 4

typedef float v2f __attribute__((ext_vector_type(2)));
typedef float v4f __attribute__((ext_vector_type(4)));
typedef __bf16 bf16x8 __attribute__((ext_vector_type(8)));

__device__ __forceinline__ float fast_exp2(float x) {
    return __builtin_amdgcn_exp2f(x);
}

// DPP row_shr move (VALU, no DS pipe); invalid source lanes read 0.
template <int CTRL>
__device__ __forceinline__ float dpp_mov(float x) {
    int r = __builtin_amdgcn_update_dpp(0, __builtin_bit_cast(int, x),
                                        CTRL, 0xf, 0xf, true);
    return __builtin_bit_cast(float, r);
}
// Sum over the 16 lanes of each row16 (= quad); result valid in lane lm==0.
__device__ __forceinline__ float rowsum16(float x) {
    x += dpp_mov<0x118>(x);   // row_shr:8
    x += dpp_mov<0x114>(x);   // row_shr:4
    x += dpp_mov<0x112>(x);   // row_shr:2
    x += dpp_mov<0x111>(x);   // row_shr:1
    return x;
}

// qkv. Grid (NN/32, BB); block 256 = 8 i-groups x 32 n.
// qbh[b][n][8] bf16, kbh[b][m][8] bf16 (k*SCALE), vf[b][n][8] fp32.
// Zeros attab[b][9][N].
__global__ __launch_bounds__(256) void qkv_kernel(
        const float* __restrict__ x,
        const float* __restrict__ Wq, const float* __restrict__ Wk,
        const float* __restrict__ Wv,
        __bf16* __restrict__ qbh, __bf16* __restrict__ kbh,
        float* __restrict__ vf, float* __restrict__ attab) {
    __shared__ float sw[3 * CI * CC];     // 6 KB: Wq | Wk*SCALE | Wv
    __shared__ unsigned short sq[32 * 8]; // bf16 tile [n_local][i]
    __shared__ unsigned short sk[32 * 8];
    __shared__ float sv[32 * 8];          // fp32 tile [n_local][i]
    const int t = threadIdx.x;
    const int i  = t >> 5;
    const int nl = t & 31;
    const int b  = blockIdx.y;
    const int n0 = blockIdx.x * 32;

    for (int idx = t; idx < CI * CC; idx += 256) {
        sw[idx]                = Wq[idx];
        sw[CI * CC + idx]      = Wk[idx] * SCALE;
        sw[2 * CI * CC + idx]  = Wv[idx];
    }
    int lin = (blockIdx.y * (NN / 32) + blockIdx.x) * 256 + t;
    for (int idx = lin; idx < BB * 9 * NN; idx += BB * NN * CI) attab[idx] = 0.f;
    __syncthreads();

    const int n = n0 + nl;
    const float* xp = x + ((size_t)b * CC) * NN + n;
    const v4f* wq4 = (const v4f*)(sw + i * CC);
    const v4f* wk4 = (const v4f*)(sw + CI * CC + i * CC);
    const v4f* wv4 = (const v4f*)(sw + 2 * CI * CC + i * CC);
    float qa = 0.f, ka = 0.f, va = 0.f;
#pragma unroll 4
    for (int c4 = 0; c4 < CC / 4; ++c4) {
        v4f wq = wq4[c4], wk = wk4[c4], wv = wv4[c4];   // LDS broadcast b128
        float x0 = xp[(size_t)(c4 * 4 + 0) * NN];
        float x1 = xp[(size_t)(c4 * 4 + 1) * NN];
        float x2 = xp[(size_t)(c4 * 4 + 2) * NN];
        float x3 = xp[(size_t)(c4 * 4 + 3) * NN];
        qa = fmaf(wq.x, x0, qa); ka = fmaf(wk.x, x0, ka); va = fmaf(wv.x, x0, va);
        qa = fmaf(wq.y, x1, qa); ka = fmaf(wk.y, x1, ka); va = fmaf(wv.y, x1, va);
        qa = fmaf(wq.z, x2, qa); ka = fmaf(wk.z, x2, ka); va = fmaf(wv.z, x2, va);
        qa = fmaf(wq.w, x3, qa); ka = fmaf(wk.w, x3, ka); va = fmaf(wv.w, x3, va);
    }
    __bf16 qb = (__bf16)qa, kb2 = (__bf16)ka;
    sq[nl * 8 + i] = *(unsigned short*)&qb;
    sk[nl * 8 + i] = *(unsigned short*)&kb2;
    sv[nl * 8 + i] = va;
    __syncthreads();
    if (t < 32) {
        *(uint4*)(qbh + ((size_t)b * NN + n0 + t) * 8) = *(const uint4*)(sq + t * 8);
        *(uint4*)(kbh + ((size_t)b * NN + n0 + t) * 8) = *(const uint4*)(sk + t * 8);
    }
    if (t < 64) {   // vf: 32 n x 32B, fully coalesced 1KB store
        int n2 = t >> 1, h = t & 1;
        *(v4f*)(vf + ((size_t)b * NN + n0 + n2) * 8 + h * 4) =
            *(const v4f*)(sv + n2 * 8 + h * 4);
    }
}

// S^T-orientation MFMA + register PV. NO LDS, no transpose, no lgkm chain.
// S' = K·Q^T tile via mfma_16x16x32_bf16 with A = K rows (m), B = Q cols (n):
// C-layout -> lane (quad,lm) holds col n = nc+lm (DISTINCT per lane), rows
// m = m0+quad*4+r. PV in fp32 registers: acc[r][i] += e_r * v[i][n], v loaded
// once per chunk as 2 coalesced b128 (fixes R10's 16x-redundant quad-broadcast
// loads, the measured 148us disaster). A is zeroed for k>=8, so B (qfrag) can
// be garbage there -> unconditional load, no per-iter branch.
// Epilogue: DPP row_shr tree (pure VALU) reduces each quad's 16 lm-partials;
// lane lm==0 per quad does the atomics (144 lane-atomics/wave, same as R9).
// |scores| < ~2 -> exp without max-subtraction safe (shift-invariant).
// Grid (64, NSPLIT, BB) = 2048 blocks x 4 waves; wave = one 16-m tile.
__global__ __launch_bounds__(256) void att_kernel(
        const __bf16* __restrict__ qbh, const __bf16* __restrict__ kbh,
        const float* __restrict__ vf, float* __restrict__ attab) {
    const int t = threadIdx.x;
    const int w    = t >> 6;
    const int l    = t & 63;
    const int quad = l >> 4;
    const int lm   = l & 15;
    const int b  = blockIdx.z;
    const int m0 = blockIdx.x * 64 + w * 16;
    const int nbase = blockIdx.y * (NN / NSPLIT);

    bf16x8 zero8;
#pragma unroll
    for (int z = 0; z < 8; ++z) zero8[z] = (__bf16)0.0f;

    // A-frag: A[row=lm][k=quad*8+j] = K[m0+lm][ci=j] for quad 0, else 0.
    bf16x8 kfrag = zero8;
    if (quad == 0)
        kfrag = *(const bf16x8*)(kbh + ((size_t)b * NN + m0 + lm) * 8);

    const __bf16* qrow = qbh + (size_t)b * NN * 8;
    const float*  vrow = vf  + (size_t)b * NN * 8;

    v2f acc[4][4];
    float es[4];
#pragma unroll
    for (int r = 0; r < 4; ++r) {
        es[r] = 0.f;
#pragma unroll
        for (int j = 0; j < 4; ++j) acc[r][j] = (v2f){0.f, 0.f};
    }

#pragma unroll 2
    for (int ch = 0; ch < (NN / NSPLIT) / 16; ++ch) {
        const int n = nbase + ch * 16 + lm;            // per-lane distinct
        // B-frag: B[k=quad*8+j][col=lm] = Q[n][ci=j] (k>=8 garbage, A=0 there)
        bf16x8 qfrag = *(const bf16x8*)(qrow + (size_t)n * 8);
        v4f vlo = *(const v4f*)(vrow + (size_t)n * 8);     // coalesced 32B/lane
        v4f vhi = *(const v4f*)(vrow + (size_t)n * 8 + 4);

        v4f d = __builtin_amdgcn_mfma_f32_16x16x32_bf16(
            kfrag, qfrag, (v4f){0.f, 0.f, 0.f, 0.f}, 0, 0, 0);

        float dv[4] = {d.x, d.y, d.z, d.w};   // rows m = m0+quad*4+r, col n
#pragma unroll
        for (int r = 0; r < 4; ++r) {
            float e = fast_exp2(dv[r]);
            es[r] += e;
            v2f e2 = {e, e};
            acc[r][0] = __builtin_elementwise_fma(e2, (v2f){vlo.x, vlo.y}, acc[r][0]);
            acc[r][1] = __builtin_elementwise_fma(e2, (v2f){vlo.z, vlo.w}, acc[r][1]);
            acc[r][2] = __builtin_elementwise_fma(e2, (v2f){vhi.x, vhi.y}, acc[r][2]);
            acc[r][3] = __builtin_elementwise_fma(e2, (v2f){vhi.z, vhi.w}, acc[r][3]);
        }
    }

    // Reduce the 16 lm-partials within each quad (DPP, VALU-only), then
    // lane lm==0 of each quad atomically adds its 4 m-rows x 9 values.
    float* ap = attab + (size_t)b * 9 * NN;
#pragma unroll
    for (int r = 0; r < 4; ++r) {
        const int m = m0 + quad * 4 + r;
        float vals[9] = {acc[r][0].x, acc[r][0].y, acc[r][1].x, acc[r][1].y,
                         acc[r][2].x, acc[r][2].y, acc[r][3].x, acc[r][3].y,
                         es[r]};
#pragma unroll
        for (int i = 0; i < 9; ++i) vals[i] = rowsum16(vals[i]);
        if (lm == 0) {
#pragma unroll
            for (int i = 0; i < 9; ++i)
                atomicAdd(ap + (size_t)i * NN + m, vals[i]);
        }
    }
}

// out. Grid (NN/1024, CC, BB); block 256; float4 per thread.
__global__ __launch_bounds__(256) void out_kernel(
        const float* __restrict__ x, const float* __restrict__ Wout,
        const float* __restrict__ attab, float* __restrict__ out) {
    const int t = threadIdx.x;
    const int c = blockIdx.y;
    const int b = blockIdx.z;
    const int m = (blockIdx.x * 256 + t) * 4;
    const float* ap = attab + (size_t)b * 9 * NN + m;
    v4f sum = *(const v4f*)(ap + (size_t)8 * NN);
    v4f s = {0.f, 0.f, 0.f, 0.f};
#pragma unroll
    for (int i = 0; i < CI; ++i) {
        float wgt = Wout[c * CI + i];               // uniform -> s_load
        v4f a = *(const v4f*)(ap + (size_t)i * NN);
        s.x = fmaf(wgt, a.x, s.x);
        s.y = fmaf(wgt, a.y, s.y);
        s.z = fmaf(wgt, a.z, s.z);
        s.w = fmaf(wgt, a.w, s.w);
    }
    size_t o = ((size_t)b * CC + c) * NN + m;
    v4f xv = *(const v4f*)(x + o);
    v4f r;
    r.x = xv.x + GAMMA * (s.x / sum.x);
    r.y = xv.y + GAMMA * (s.y / sum.y);
    r.z = xv.z + GAMMA * (s.z / sum.z);
    r.w = xv.w + GAMMA * (s.w / sum.w);
    *(v4f*)(out + o) = r;
}

extern "C" void kernel_launch(void* const* d_in, const int* in_sizes, int n_in,
                              void* d_out, int out_size, void* d_ws, size_t ws_size,
                              hipStream_t stream) {
    const float* x    = (const float*)d_in[0];
    const float* Wq   = (const float*)d_in[1];
    const float* Wk   = (const float*)d_in[2];
    const float* Wv   = (const float*)d_in[3];
    const float* Wout = (const float*)d_in[4];
    float* out = (float*)d_out;

    // ws: qbh [B][N][8] bf16 | kbh [B][N][8] bf16 | vf [B][N][8] fp32 |
    //     attab [B][9][N] fp32
    __bf16* qbh = (__bf16*)d_ws;
    __bf16* kbh = qbh + (size_t)BB * NN * 8;
    float*  vf  = (float*)(kbh + (size_t)BB * NN * 8);
    float* attab = vf + (size_t)BB * NN * 8;

    qkv_kernel<<<dim3(NN / 32, BB), 256, 0, stream>>>(x, Wq, Wk, Wv, qbh, kbh, vf, attab);
    att_kernel<<<dim3(NN / 64, NSPLIT, BB), 256, 0, stream>>>(qbh, kbh, vf, attab);
    out_kernel<<<dim3(NN / 1024, CC, BB), 256, 0, stream>>>(x, Wout, attab, out);
}